// Round 12
// baseline (208.994 us; speedup 1.0000x reference)
//
#include <hip/hip_runtime.h>
#include <hip/hip_bf16.h>

// CausalSelfAttention  B=1, T=4096, C=768, H=12, hd=64
// Round 12: flash v10 — balanced 3-partition block->work map (every CU's
//   triple of blocks sums to 97/98 k-iters vs 64..128 gradient before),
//   v_perm-style P packing. Rest unchanged from R11.

#define T_SEQ 4096
#define C_DIM 768
#define C3    2304
#define NH    12
#define HD    64

typedef __attribute__((ext_vector_type(8))) short bf16x8;
typedef __attribute__((ext_vector_type(4))) short bf16x4;
typedef __attribute__((ext_vector_type(4))) float f32x4;

__device__ inline unsigned short f2bf(float f) {
  union { float f; unsigned u; } v; v.f = f;
  unsigned r = v.u + 0x7fff + ((v.u >> 16) & 1);  // RTNE
  return (unsigned short)(r >> 16);
}
// pack two fp32 -> two truncated bf16 in one word ((a>>16)|(b&hi)) = v_perm
__device__ inline unsigned pack_bf16_trunc(float a, float b) {
  union { float f; unsigned u; } x, y; x.f = a; y.f = b;
  return (x.u >> 16) | (y.u & 0xffff0000u);
}

__device__ inline void gl2lds16(const void* g, void* l) {
  __builtin_amdgcn_global_load_lds(
      (const __attribute__((address_space(1))) unsigned int*)g,
      (__attribute__((address_space(3))) unsigned int*)l, 16, 0, 0);
}

#if __has_builtin(__builtin_amdgcn_exp2f)
#define EXP2F(x) __builtin_amdgcn_exp2f(x)
#else
#define EXP2F(x) exp2f(x)
#endif

// ---------------------------------------------------------------------------
// fused prep: conv x->bf16 | transpose w_qkv | transpose w_proj
// ---------------------------------------------------------------------------
#define NB_CONV  (T_SEQ * C_DIM / 2048)          // 1536
#define NB_TQKV  ((C3 / 32) * (C_DIM / 32))      // 1728
#define NB_TPROJ ((C_DIM / 32) * (C_DIM / 32))   // 576

__global__ __launch_bounds__(256) void prep_fused(
    const float* __restrict__ x, const float* __restrict__ w_qkv,
    const float* __restrict__ w_proj, unsigned short* __restrict__ xb,
    unsigned short* __restrict__ wqkvT, unsigned short* __restrict__ wprojT) {
  __shared__ float t[32][33];
  const int b = blockIdx.x;
  const int tid = threadIdx.x;

  if (b < NB_CONV) {
    int i = (b * 256 + tid) * 8;
    float4 v0 = *(const float4*)(x + i);
    float4 v1 = *(const float4*)(x + i + 4);
    unsigned short o[8] = {f2bf(v0.x), f2bf(v0.y), f2bf(v0.z), f2bf(v0.w),
                           f2bf(v1.x), f2bf(v1.y), f2bf(v1.z), f2bf(v1.w)};
    *(uint4*)(xb + i) = *(uint4*)o;
    return;
  }
  const float* in;
  unsigned short* outT;
  int R, Cc, bi;
  if (b < NB_CONV + NB_TQKV) {
    in = w_qkv; outT = wqkvT; R = C_DIM; Cc = C3; bi = b - NB_CONV;
  } else {
    in = w_proj; outT = wprojT; R = C_DIM; Cc = C_DIM; bi = b - NB_CONV - NB_TQKV;
  }
  const int tx = tid & 31, ty = tid >> 5;
  const int c0 = (bi % (Cc / 32)) * 32, r0 = (bi / (Cc / 32)) * 32;
#pragma unroll
  for (int i = 0; i < 4; ++i) {
    int r = ty + i * 8;
    t[r][tx] = in[(size_t)(r0 + r) * Cc + c0 + tx];
  }
  __syncthreads();
#pragma unroll
  for (int i = 0; i < 4; ++i) {
    int c = ty + i * 8;
    outT[(size_t)(c0 + c) * R + r0 + tx] = f2bf(t[tx][c]);
  }
}

// ---------------------------------------------------------------------------
// gemm1: qkv = xb @ wqkvT^T + b_qkv; V blocks write k-permuted vTp directly.
// ---------------------------------------------------------------------------
__global__ __launch_bounds__(256) void gemm_qkv(
    const unsigned short* __restrict__ A, const unsigned short* __restrict__ Bt,
    const float* __restrict__ bias, unsigned short* __restrict__ Cq,
    unsigned short* __restrict__ vTp, int M, int N, int K) {
  __shared__ unsigned short As[128 * 32];
  __shared__ unsigned short Bs[128 * 32];
  const int tid = threadIdx.x;
  const int wave = tid >> 6, lane = tid & 63;
  const int lo = lane & 15, g8 = lane >> 4;
  const int wm = wave >> 1, wn = wave & 1;
  const int bm = blockIdx.y * 128, bn = blockIdx.x * 128;
  const int lrow = lane >> 2;
  const int lcol = (lane & 3) * 8;

  f32x4 acc[4][4];
#pragma unroll
  for (int mt = 0; mt < 4; ++mt)
#pragma unroll
    for (int nt = 0; nt < 4; ++nt) acc[mt][nt] = (f32x4){0.f, 0.f, 0.f, 0.f};

  const unsigned short* Abase = A + (size_t)bm * K;
  const unsigned short* Bbase = Bt + (size_t)bn * K;

  for (int k0 = 0; k0 < K; k0 += 32) {
    __syncthreads();
#pragma unroll
    for (int c = 0; c < 2; ++c) {
      const int r = wave * 32 + c * 16;
      gl2lds16(Abase + (size_t)(r + lrow) * K + k0 + lcol, As + r * 32 + lane * 8);
      gl2lds16(Bbase + (size_t)(r + lrow) * K + k0 + lcol, Bs + r * 32 + lane * 8);
    }
    __syncthreads();

    bf16x8 a[4], b[4];
#pragma unroll
    for (int mt = 0; mt < 4; ++mt)
      a[mt] = *(const bf16x8*)(As + (wm * 64 + mt * 16 + lo) * 32 + g8 * 8);
#pragma unroll
    for (int nt = 0; nt < 4; ++nt)
      b[nt] = *(const bf16x8*)(Bs + (wn * 64 + nt * 16 + lo) * 32 + g8 * 8);
#pragma unroll
    for (int mt = 0; mt < 4; ++mt)
#pragma unroll
      for (int nt = 0; nt < 4; ++nt)
        acc[mt][nt] = __builtin_amdgcn_mfma_f32_16x16x32_bf16(a[mt], b[nt], acc[mt][nt], 0, 0, 0);
  }

  if (bn < 2 * C_DIM) {
#pragma unroll
    for (int nt = 0; nt < 4; ++nt) {
      const int n = bn + wn * 64 + nt * 16 + lo;
      const float bv = bias[n];
#pragma unroll
      for (int mt = 0; mt < 4; ++mt)
#pragma unroll
        for (int r = 0; r < 4; ++r) {
          const int m = bm + wm * 64 + mt * 16 + g8 * 4 + r;
          Cq[(size_t)m * C3 + n] = f2bf(acc[mt][nt][r] + bv);
        }
    }
  } else {
#pragma unroll
    for (int nt = 0; nt < 4; ++nt) {
      const int n = bn + wn * 64 + nt * 16 + lo;
      const float bv = bias[n];
      unsigned short* row = vTp + (size_t)(n - 2 * C_DIM) * T_SEQ;
#pragma unroll
      for (int mt = 0; mt < 4; ++mt) {
        const int mbase = (bm + wm * 64 + mt * 16 + g8 * 4) & ~31;
        bf16x4 o4;
#pragma unroll
        for (int r = 0; r < 4; ++r) o4[r] = (short)f2bf(acc[mt][nt][r] + bv);
        *(bf16x4*)(row + mbase + 8 * g8 + 4 * (mt & 1)) = o4;
      }
    }
  }
}

// ---------------------------------------------------------------------------
// gemm2: bf16 MFMA GEMM, B-transposed input, fp32 out (unchanged)
// ---------------------------------------------------------------------------
__global__ __launch_bounds__(256) void gemm_bt_mfma(
    const unsigned short* __restrict__ A, const unsigned short* __restrict__ Bt,
    const float* __restrict__ bias, float* __restrict__ C,
    int M, int N, int K) {
  __shared__ unsigned short As[128 * 32];
  __shared__ unsigned short Bs[128 * 32];
  const int tid = threadIdx.x;
  const int wave = tid >> 6, lane = tid & 63;
  const int lo = lane & 15, g8 = lane >> 4;
  const int wm = wave >> 1, wn = wave & 1;
  const int bm = blockIdx.y * 128, bn = blockIdx.x * 128;
  const int lrow = lane >> 2;
  const int lcol = (lane & 3) * 8;

  f32x4 acc[4][4];
#pragma unroll
  for (int mt = 0; mt < 4; ++mt)
#pragma unroll
    for (int nt = 0; nt < 4; ++nt) acc[mt][nt] = (f32x4){0.f, 0.f, 0.f, 0.f};

  const unsigned short* Abase = A + (size_t)bm * K;
  const unsigned short* Bbase = Bt + (size_t)bn * K;

  for (int k0 = 0; k0 < K; k0 += 32) {
    __syncthreads();
#pragma unroll
    for (int c = 0; c < 2; ++c) {
      const int r = wave * 32 + c * 16;
      gl2lds16(Abase + (size_t)(r + lrow) * K + k0 + lcol, As + r * 32 + lane * 8);
      gl2lds16(Bbase + (size_t)(r + lrow) * K + k0 + lcol, Bs + r * 32 + lane * 8);
    }
    __syncthreads();

    bf16x8 a[4], b[4];
#pragma unroll
    for (int mt = 0; mt < 4; ++mt)
      a[mt] = *(const bf16x8*)(As + (wm * 64 + mt * 16 + lo) * 32 + g8 * 8);
#pragma unroll
    for (int nt = 0; nt < 4; ++nt)
      b[nt] = *(const bf16x8*)(Bs + (wn * 64 + nt * 16 + lo) * 32 + g8 * 8);
#pragma unroll
    for (int mt = 0; mt < 4; ++mt)
#pragma unroll
      for (int nt = 0; nt < 4; ++nt)
        acc[mt][nt] = __builtin_amdgcn_mfma_f32_16x16x32_bf16(a[mt], b[nt], acc[mt][nt], 0, 0, 0);
  }

#pragma unroll
  for (int nt = 0; nt < 4; ++nt) {
    const int n = bn + wn * 64 + nt * 16 + lo;
    const float bv = bias[n];
#pragma unroll
    for (int mt = 0; mt < 4; ++mt)
#pragma unroll
      for (int r = 0; r < 4; ++r) {
        const int m = bm + wm * 64 + mt * 16 + g8 * 4 + r;
        C[(size_t)m * N + n] = acc[mt][nt][r] + bv;
      }
  }
}

// ---------------------------------------------------------------------------
// flash v10: v9 + balanced block->(qt,h) map + v_perm P packing.
// Map: bin = bx&255, role = bx>>8; s = bin>>6, r = bin&63, half = r>>5,
//      j = r&31.  role0: iters=64-j, h=2s+half; role1: iters=32-j, h=2s+half;
//      role2: iters=2j+1+half, h=8+s.  Triple sums 97/98 for every bin;
//      blocks {bin, bin+256, bin+512} co-schedule on one CU (empirical
//      round-robin dispatch), so per-CU work is flat. Covers each (qt,h) once.
// ---------------------------------------------------------------------------
__global__ __launch_bounds__(256) void flash_attn_mfma10(
    const unsigned short* __restrict__ qkv,   // [T][2304] bf16 (Q,K valid)
    const unsigned short* __restrict__ vTp,   // [768][T] bf16, k-permuted
    unsigned short* __restrict__ out) {       // [T][768] bf16
  __shared__ unsigned short Ks[2][64 * 64];
  __shared__ unsigned short Vs[2][64 * 64];

  const int bx = blockIdx.x;
  const int bin = bx & 255, role = bx >> 8;
  const int s = bin >> 6, r_ = bin & 63, half = r_ >> 5, j = r_ & 31;
  int v_, h;
  if (role == 0)      { v_ = 64 - j;           h = 2 * s + half; }
  else if (role == 1) { v_ = 32 - j;           h = 2 * s + half; }
  else                { v_ = 2 * j + 1 + half; h = 8 + s; }
  const int qt = v_ - 1;
  const int q0 = qt * 64;
  const int tid = threadIdx.x;
  const int w = tid >> 6;
  const int lane = tid & 63;
  const int lo = lane & 15;
  const int g = lane >> 4;
  const int lo7 = lo & 7;
  const float qscale = 0.125f * 1.44269504f;  // 1/sqrt(64) * log2(e)

  const unsigned short* Kg = qkv + C_DIM + h * HD;           // row stride C3
  const unsigned short* Vg = vTp + (size_t)(h * HD) * T_SEQ; // row stride T_SEQ

  const int drow = tid >> 3;                    // 0..31
  const int dslot = (tid & 7) * 8;
  const int dsrc = ((tid & 7) ^ (drow & 7)) * 8;

  // Q B-frags direct from global (one-time)
  bf16x8 qb[2];
#pragma unroll
  for (int dh = 0; dh < 2; ++dh)
    qb[dh] = *(const bf16x8*)(
        qkv + (size_t)(q0 + w * 16 + lo) * C3 + h * HD + dh * 32 + g * 8);

  // prologue: DMA tile 0
#pragma unroll
  for (int p = 0; p < 2; ++p) {
    const int r = p * 32 + drow;
    gl2lds16(Kg + (size_t)r * C3 + dsrc, Ks[0] + r * 64 + dslot);
    gl2lds16(Vg + (size_t)r * T_SEQ + dsrc, Vs[0] + r * 64 + dslot);
  }
  __syncthreads();

  float l_i = 0.f;
  f32x4 o_acc[4];
#pragma unroll
  for (int dt = 0; dt < 4; ++dt) o_acc[dt] = (f32x4){0.f, 0.f, 0.f, 0.f};

  for (int t = 0; t <= qt; ++t) {
    const int cur = t & 1;
    if (t < qt) {
      const int k0n = (t + 1) * 64;
#pragma unroll
      for (int p = 0; p < 2; ++p) {
        const int r = p * 32 + drow;
        gl2lds16(Kg + (size_t)(k0n + r) * C3 + dsrc, Ks[cur ^ 1] + r * 64 + dslot);
        gl2lds16(Vg + (size_t)r * T_SEQ + k0n + dsrc, Vs[cur ^ 1] + r * 64 + dslot);
      }
    }

    // St = K @ Q^T
    f32x4 st[4];
#pragma unroll
    for (int mt = 0; mt < 4; ++mt) st[mt] = (f32x4){0.f, 0.f, 0.f, 0.f};
#pragma unroll
    for (int mt = 0; mt < 4; ++mt)
#pragma unroll
      for (int dh = 0; dh < 2; ++dh) {
        bf16x8 a = *(const bf16x8*)(
            Ks[cur] + (mt * 16 + lo) * 64 + (((dh * 4 + g) ^ lo7) * 8));
        st[mt] = __builtin_amdgcn_mfma_f32_16x16x32_bf16(a, qb[dh], st[mt], 0, 0, 0);
      }

    // causal mask (last tile only) -> exact zeros after exp2
    if (t == qt) {
      const int qloc = w * 16 + lo;
#pragma unroll
      for (int mt = 0; mt < 4; ++mt)
#pragma unroll
        for (int r = 0; r < 4; ++r)
          if (mt * 16 + g * 4 + r > qloc) st[mt][r] = -1e30f;
    }

    // no-max softmax: e = exp2(s*qscale); pack pairs via v_perm
    float lsum = 0.f;
    union { bf16x8 v; unsigned u[4]; } pt[2];
#pragma unroll
    for (int kh = 0; kh < 2; ++kh) {
      float e0 = EXP2F(st[kh * 2][0] * qscale);
      float e1 = EXP2F(st[kh * 2][1] * qscale);
      float e2 = EXP2F(st[kh * 2][2] * qscale);
      float e3 = EXP2F(st[kh * 2][3] * qscale);
      float f0 = EXP2F(st[kh * 2 + 1][0] * qscale);
      float f1 = EXP2F(st[kh * 2 + 1][1] * qscale);
      float f2 = EXP2F(st[kh * 2 + 1][2] * qscale);
      float f3 = EXP2F(st[kh * 2 + 1][3] * qscale);
      lsum += (e0 + e1) + (e2 + e3) + (f0 + f1) + (f2 + f3);
      pt[kh].u[0] = pack_bf16_trunc(e0, e1);
      pt[kh].u[1] = pack_bf16_trunc(e2, e3);
      pt[kh].u[2] = pack_bf16_trunc(f0, f1);
      pt[kh].u[3] = pack_bf16_trunc(f2, f3);
    }
    l_i += lsum;  // cross-lane reduce deferred to epilogue

    // O^T += V^T @ P^T
#pragma unroll
    for (int dt = 0; dt < 4; ++dt)
#pragma unroll
      for (int kh = 0; kh < 2; ++kh) {
        bf16x8 av = *(const bf16x8*)(
            Vs[cur] + (dt * 16 + lo) * 64 + (((kh * 4 + g) ^ lo7) * 8));
        o_acc[dt] = __builtin_amdgcn_mfma_f32_16x16x32_bf16(av, pt[kh].v, o_acc[dt], 0, 0, 0);
      }

    __syncthreads();  // drain prefetch DMAs + release buffer cur
  }

  // epilogue
  l_i += __shfl_xor(l_i, 16);
  l_i += __shfl_xor(l_i, 32);
  const float inv = 1.0f / l_i;
  unsigned short* Es = Ks[0];
#pragma unroll
  for (int dt = 0; dt < 4; ++dt) {
    const int chunk = (dt * 2 + (g >> 1)) ^ lo7;
#pragma unroll
    for (int r = 0; r < 4; ++r)
      Es[(w * 16 + lo) * 64 + chunk * 8 + (g & 1) * 4 + r] =
          f2bf(o_acc[dt][r] * inv);
  }
#pragma unroll
  for (int i = 0; i < 2; ++i) {
    const int row = w * 16 + i * 8 + (lane >> 3);
    bf16x8 val = *(const bf16x8*)(Es + row * 64 + (((lane & 7) ^ (row & 7)) * 8));
    *(bf16x8*)(out + (size_t)(q0 + row) * C_DIM + h * HD + (lane & 7) * 8) = val;
  }
}

// ---------------------------------------------------------------------------
extern "C" void kernel_launch(void* const* d_in, const int* in_sizes, int n_in,
                              void* d_out, int out_size, void* d_ws, size_t ws_size,
                              hipStream_t stream) {
  const float* x      = (const float*)d_in[0];
  const float* w_qkv  = (const float*)d_in[1];
  const float* b_qkv  = (const float*)d_in[2];
  const float* w_proj = (const float*)d_in[3];
  const float* b_proj = (const float*)d_in[4];
  float* out = (float*)d_out;

  unsigned short* xb     = (unsigned short*)d_ws;               // [4096,768]
  unsigned short* wqkvT  = xb + (size_t)T_SEQ * C_DIM;          // [2304,768]
  unsigned short* wprojT = wqkvT + (size_t)C3 * C_DIM;          // [768,768]
  unsigned short* qkv    = wprojT + (size_t)C_DIM * C_DIM;      // [4096,2304]
  unsigned short* vTp    = qkv + (size_t)T_SEQ * C3;            // [768,4096]
  unsigned short* attnb  = vTp + (size_t)C_DIM * T_SEQ;         // [4096,768]

  prep_fused<<<NB_CONV + NB_TQKV + NB_TPROJ, 256, 0, stream>>>(
      x, w_qkv, w_proj, xb, wqkvT, wprojT);

  gemm_qkv<<<dim3(C3 / 128, T_SEQ / 128), 256, 0, stream>>>(
      xb, wqkvT, b_qkv, qkv, vTp, T_SEQ, C3, C_DIM);

  flash_attn_mfma10<<<T_SEQ / 64 * NH, 256, 0, stream>>>(qkv, vTp, attnb);

  gemm_bt_mfma<<<dim3(C_DIM / 128, T_SEQ / 128), 256, 0, stream>>>(
      attnb, wprojT, b_proj, out, T_SEQ, C_DIM, C_DIM);
}

// Round 13
// 195.782 us; speedup vs baseline: 1.0675x; 1.0675x over previous
//
#include <hip/hip_runtime.h>
#include <hip/hip_bf16.h>

// CausalSelfAttention  B=1, T=4096, C=768, H=12, hd=64
// Round 13: revert flash map to monotone LPT (R12's balanced map broke
//   L2/L3 stream locality: FETCH 15->49MB, 65->78.5us). Keep v_perm pack.
//   GEMMs: BK=64 with XOR-swizzled LDS (halves barriers, conflict-free).

#define T_SEQ 4096
#define C_DIM 768
#define C3    2304
#define NH    12
#define HD    64

typedef __attribute__((ext_vector_type(8))) short bf16x8;
typedef __attribute__((ext_vector_type(4))) short bf16x4;
typedef __attribute__((ext_vector_type(4))) float f32x4;

__device__ inline unsigned short f2bf(float f) {
  union { float f; unsigned u; } v; v.f = f;
  unsigned r = v.u + 0x7fff + ((v.u >> 16) & 1);  // RTNE
  return (unsigned short)(r >> 16);
}
// pack two fp32 -> two truncated bf16 in one word (v_perm-able)
__device__ inline unsigned pack_bf16_trunc(float a, float b) {
  union { float f; unsigned u; } x, y; x.f = a; y.f = b;
  return (x.u >> 16) | (y.u & 0xffff0000u);
}

__device__ inline void gl2lds16(const void* g, void* l) {
  __builtin_amdgcn_global_load_lds(
      (const __attribute__((address_space(1))) unsigned int*)g,
      (__attribute__((address_space(3))) unsigned int*)l, 16, 0, 0);
}

#if __has_builtin(__builtin_amdgcn_exp2f)
#define EXP2F(x) __builtin_amdgcn_exp2f(x)
#else
#define EXP2F(x) exp2f(x)
#endif

// ---------------------------------------------------------------------------
// fused prep: conv x->bf16 | transpose w_qkv | transpose w_proj
// ---------------------------------------------------------------------------
#define NB_CONV  (T_SEQ * C_DIM / 2048)          // 1536
#define NB_TQKV  ((C3 / 32) * (C_DIM / 32))      // 1728
#define NB_TPROJ ((C_DIM / 32) * (C_DIM / 32))   // 576

__global__ __launch_bounds__(256) void prep_fused(
    const float* __restrict__ x, const float* __restrict__ w_qkv,
    const float* __restrict__ w_proj, unsigned short* __restrict__ xb,
    unsigned short* __restrict__ wqkvT, unsigned short* __restrict__ wprojT) {
  __shared__ float t[32][33];
  const int b = blockIdx.x;
  const int tid = threadIdx.x;

  if (b < NB_CONV) {
    int i = (b * 256 + tid) * 8;
    float4 v0 = *(const float4*)(x + i);
    float4 v1 = *(const float4*)(x + i + 4);
    unsigned short o[8] = {f2bf(v0.x), f2bf(v0.y), f2bf(v0.z), f2bf(v0.w),
                           f2bf(v1.x), f2bf(v1.y), f2bf(v1.z), f2bf(v1.w)};
    *(uint4*)(xb + i) = *(uint4*)o;
    return;
  }
  const float* in;
  unsigned short* outT;
  int R, Cc, bi;
  if (b < NB_CONV + NB_TQKV) {
    in = w_qkv; outT = wqkvT; R = C_DIM; Cc = C3; bi = b - NB_CONV;
  } else {
    in = w_proj; outT = wprojT; R = C_DIM; Cc = C_DIM; bi = b - NB_CONV - NB_TQKV;
  }
  const int tx = tid & 31, ty = tid >> 5;
  const int c0 = (bi % (Cc / 32)) * 32, r0 = (bi / (Cc / 32)) * 32;
#pragma unroll
  for (int i = 0; i < 4; ++i) {
    int r = ty + i * 8;
    t[r][tx] = in[(size_t)(r0 + r) * Cc + c0 + tx];
  }
  __syncthreads();
#pragma unroll
  for (int i = 0; i < 4; ++i) {
    int c = ty + i * 8;
    outT[(size_t)(c0 + c) * R + r0 + tx] = f2bf(t[tx][c]);
  }
}

// ---------------------------------------------------------------------------
// gemm1: qkv = xb @ wqkvT^T + b_qkv; V blocks write k-permuted vTp directly.
// BK=64, XOR-swizzled LDS (chunk c of row r at slot c^(r&7)); 12 k-iters.
// ---------------------------------------------------------------------------
__global__ __launch_bounds__(256) void gemm_qkv(
    const unsigned short* __restrict__ A, const unsigned short* __restrict__ Bt,
    const float* __restrict__ bias, unsigned short* __restrict__ Cq,
    unsigned short* __restrict__ vTp, int M, int N, int K) {
  __shared__ unsigned short As[128 * 64];
  __shared__ unsigned short Bs[128 * 64];
  const int tid = threadIdx.x;
  const int wave = tid >> 6, lane = tid & 63;
  const int lo = lane & 15, g8 = lane >> 4;
  const int lo7 = lo & 7;
  const int wm = wave >> 1, wn = wave & 1;
  const int bm = blockIdx.y * 128, bn = blockIdx.x * 128;
  const int drow8 = lane >> 3;               // 0..7
  const int dslot = (lane & 7) * 8;
  const int dsrc = ((lane & 7) ^ drow8) * 8; // swizzled source chunk

  f32x4 acc[4][4];
#pragma unroll
  for (int mt = 0; mt < 4; ++mt)
#pragma unroll
    for (int nt = 0; nt < 4; ++nt) acc[mt][nt] = (f32x4){0.f, 0.f, 0.f, 0.f};

  const unsigned short* Abase = A + (size_t)bm * K;
  const unsigned short* Bbase = Bt + (size_t)bn * K;

  for (int k0 = 0; k0 < K; k0 += 64) {
    __syncthreads();
#pragma unroll
    for (int p = 0; p < 4; ++p) {
      const int r = p * 32 + wave * 8 + drow8;
      gl2lds16(Abase + (size_t)r * K + k0 + dsrc, As + r * 64 + dslot);
      gl2lds16(Bbase + (size_t)r * K + k0 + dsrc, Bs + r * 64 + dslot);
    }
    __syncthreads();

#pragma unroll
    for (int kk = 0; kk < 2; ++kk) {
      bf16x8 a[4], b[4];
#pragma unroll
      for (int mt = 0; mt < 4; ++mt)
        a[mt] = *(const bf16x8*)(
            As + (wm * 64 + mt * 16 + lo) * 64 + (((kk * 4 + g8) ^ lo7) * 8));
#pragma unroll
      for (int nt = 0; nt < 4; ++nt)
        b[nt] = *(const bf16x8*)(
            Bs + (wn * 64 + nt * 16 + lo) * 64 + (((kk * 4 + g8) ^ lo7) * 8));
#pragma unroll
      for (int mt = 0; mt < 4; ++mt)
#pragma unroll
        for (int nt = 0; nt < 4; ++nt)
          acc[mt][nt] = __builtin_amdgcn_mfma_f32_16x16x32_bf16(a[mt], b[nt], acc[mt][nt], 0, 0, 0);
    }
  }

  if (bn < 2 * C_DIM) {
#pragma unroll
    for (int nt = 0; nt < 4; ++nt) {
      const int n = bn + wn * 64 + nt * 16 + lo;
      const float bv = bias[n];
#pragma unroll
      for (int mt = 0; mt < 4; ++mt)
#pragma unroll
        for (int r = 0; r < 4; ++r) {
          const int m = bm + wm * 64 + mt * 16 + g8 * 4 + r;
          Cq[(size_t)m * C3 + n] = f2bf(acc[mt][nt][r] + bv);
        }
    }
  } else {
#pragma unroll
    for (int nt = 0; nt < 4; ++nt) {
      const int n = bn + wn * 64 + nt * 16 + lo;
      const float bv = bias[n];
      unsigned short* row = vTp + (size_t)(n - 2 * C_DIM) * T_SEQ;
#pragma unroll
      for (int mt = 0; mt < 4; ++mt) {
        const int mbase = (bm + wm * 64 + mt * 16 + g8 * 4) & ~31;
        bf16x4 o4;
#pragma unroll
        for (int r = 0; r < 4; ++r) o4[r] = (short)f2bf(acc[mt][nt][r] + bv);
        *(bf16x4*)(row + mbase + 8 * g8 + 4 * (mt & 1)) = o4;
      }
    }
  }
}

// ---------------------------------------------------------------------------
// gemm2: bf16 MFMA GEMM, B^T input, fp32 out. BK=64 swizzled (as gemm1).
// ---------------------------------------------------------------------------
__global__ __launch_bounds__(256) void gemm_bt_mfma(
    const unsigned short* __restrict__ A, const unsigned short* __restrict__ Bt,
    const float* __restrict__ bias, float* __restrict__ C,
    int M, int N, int K) {
  __shared__ unsigned short As[128 * 64];
  __shared__ unsigned short Bs[128 * 64];
  const int tid = threadIdx.x;
  const int wave = tid >> 6, lane = tid & 63;
  const int lo = lane & 15, g8 = lane >> 4;
  const int lo7 = lo & 7;
  const int wm = wave >> 1, wn = wave & 1;
  const int bm = blockIdx.y * 128, bn = blockIdx.x * 128;
  const int drow8 = lane >> 3;
  const int dslot = (lane & 7) * 8;
  const int dsrc = ((lane & 7) ^ drow8) * 8;

  f32x4 acc[4][4];
#pragma unroll
  for (int mt = 0; mt < 4; ++mt)
#pragma unroll
    for (int nt = 0; nt < 4; ++nt) acc[mt][nt] = (f32x4){0.f, 0.f, 0.f, 0.f};

  const unsigned short* Abase = A + (size_t)bm * K;
  const unsigned short* Bbase = Bt + (size_t)bn * K;

  for (int k0 = 0; k0 < K; k0 += 64) {
    __syncthreads();
#pragma unroll
    for (int p = 0; p < 4; ++p) {
      const int r = p * 32 + wave * 8 + drow8;
      gl2lds16(Abase + (size_t)r * K + k0 + dsrc, As + r * 64 + dslot);
      gl2lds16(Bbase + (size_t)r * K + k0 + dsrc, Bs + r * 64 + dslot);
    }
    __syncthreads();

#pragma unroll
    for (int kk = 0; kk < 2; ++kk) {
      bf16x8 a[4], b[4];
#pragma unroll
      for (int mt = 0; mt < 4; ++mt)
        a[mt] = *(const bf16x8*)(
            As + (wm * 64 + mt * 16 + lo) * 64 + (((kk * 4 + g8) ^ lo7) * 8));
#pragma unroll
      for (int nt = 0; nt < 4; ++nt)
        b[nt] = *(const bf16x8*)(
            Bs + (wn * 64 + nt * 16 + lo) * 64 + (((kk * 4 + g8) ^ lo7) * 8));
#pragma unroll
      for (int mt = 0; mt < 4; ++mt)
#pragma unroll
        for (int nt = 0; nt < 4; ++nt)
          acc[mt][nt] = __builtin_amdgcn_mfma_f32_16x16x32_bf16(a[mt], b[nt], acc[mt][nt], 0, 0, 0);
    }
  }

#pragma unroll
  for (int nt = 0; nt < 4; ++nt) {
    const int n = bn + wn * 64 + nt * 16 + lo;
    const float bv = bias[n];
#pragma unroll
    for (int mt = 0; mt < 4; ++mt)
#pragma unroll
      for (int r = 0; r < 4; ++r) {
        const int m = bm + wm * 64 + mt * 16 + g8 * 4 + r;
        C[(size_t)m * N + n] = acc[mt][nt][r] + bv;
      }
  }
}

// ---------------------------------------------------------------------------
// flash v11 = R11's v9 (monotone LPT: qt = 63 - bx/12, h = bx%12 — preserves
// K/V stream locality) + v_perm P packing. No-max softmax, reg-resident P,
// swizzled K/V double-buffer, lds-DMA staging.
// ---------------------------------------------------------------------------
__global__ __launch_bounds__(256) void flash_attn_mfma11(
    const unsigned short* __restrict__ qkv,   // [T][2304] bf16 (Q,K valid)
    const unsigned short* __restrict__ vTp,   // [768][T] bf16, k-permuted
    unsigned short* __restrict__ out) {       // [T][768] bf16
  __shared__ unsigned short Ks[2][64 * 64];
  __shared__ unsigned short Vs[2][64 * 64];

  const int qt = 63 - blockIdx.x / NH;  // monotone LPT (stream-aligned)
  const int h = blockIdx.x % NH;
  const int q0 = qt * 64;
  const int tid = threadIdx.x;
  const int w = tid >> 6;
  const int lane = tid & 63;
  const int lo = lane & 15;
  const int g = lane >> 4;
  const int lo7 = lo & 7;
  const float qscale = 0.125f * 1.44269504f;  // 1/sqrt(64) * log2(e)

  const unsigned short* Kg = qkv + C_DIM + h * HD;           // row stride C3
  const unsigned short* Vg = vTp + (size_t)(h * HD) * T_SEQ; // row stride T_SEQ

  const int drow = tid >> 3;                    // 0..31
  const int dslot = (tid & 7) * 8;
  const int dsrc = ((tid & 7) ^ (drow & 7)) * 8;

  // Q B-frags direct from global (one-time)
  bf16x8 qb[2];
#pragma unroll
  for (int dh = 0; dh < 2; ++dh)
    qb[dh] = *(const bf16x8*)(
        qkv + (size_t)(q0 + w * 16 + lo) * C3 + h * HD + dh * 32 + g * 8);

  // prologue: DMA tile 0
#pragma unroll
  for (int p = 0; p < 2; ++p) {
    const int r = p * 32 + drow;
    gl2lds16(Kg + (size_t)r * C3 + dsrc, Ks[0] + r * 64 + dslot);
    gl2lds16(Vg + (size_t)r * T_SEQ + dsrc, Vs[0] + r * 64 + dslot);
  }
  __syncthreads();

  float l_i = 0.f;
  f32x4 o_acc[4];
#pragma unroll
  for (int dt = 0; dt < 4; ++dt) o_acc[dt] = (f32x4){0.f, 0.f, 0.f, 0.f};

  for (int t = 0; t <= qt; ++t) {
    const int cur = t & 1;
    if (t < qt) {
      const int k0n = (t + 1) * 64;
#pragma unroll
      for (int p = 0; p < 2; ++p) {
        const int r = p * 32 + drow;
        gl2lds16(Kg + (size_t)(k0n + r) * C3 + dsrc, Ks[cur ^ 1] + r * 64 + dslot);
        gl2lds16(Vg + (size_t)r * T_SEQ + k0n + dsrc, Vs[cur ^ 1] + r * 64 + dslot);
      }
    }

    // St = K @ Q^T
    f32x4 st[4];
#pragma unroll
    for (int mt = 0; mt < 4; ++mt) st[mt] = (f32x4){0.f, 0.f, 0.f, 0.f};
#pragma unroll
    for (int mt = 0; mt < 4; ++mt)
#pragma unroll
      for (int dh = 0; dh < 2; ++dh) {
        bf16x8 a = *(const bf16x8*)(
            Ks[cur] + (mt * 16 + lo) * 64 + (((dh * 4 + g) ^ lo7) * 8));
        st[mt] = __builtin_amdgcn_mfma_f32_16x16x32_bf16(a, qb[dh], st[mt], 0, 0, 0);
      }

    // causal mask (last tile only) -> exact zeros after exp2
    if (t == qt) {
      const int qloc = w * 16 + lo;
#pragma unroll
      for (int mt = 0; mt < 4; ++mt)
#pragma unroll
        for (int r = 0; r < 4; ++r)
          if (mt * 16 + g * 4 + r > qloc) st[mt][r] = -1e30f;
    }

    // no-max softmax: e = exp2(s*qscale); pack pairs via v_perm
    float lsum = 0.f;
    union { bf16x8 v; unsigned u[4]; } pt[2];
#pragma unroll
    for (int kh = 0; kh < 2; ++kh) {
      float e0 = EXP2F(st[kh * 2][0] * qscale);
      float e1 = EXP2F(st[kh * 2][1] * qscale);
      float e2 = EXP2F(st[kh * 2][2] * qscale);
      float e3 = EXP2F(st[kh * 2][3] * qscale);
      float f0 = EXP2F(st[kh * 2 + 1][0] * qscale);
      float f1 = EXP2F(st[kh * 2 + 1][1] * qscale);
      float f2 = EXP2F(st[kh * 2 + 1][2] * qscale);
      float f3 = EXP2F(st[kh * 2 + 1][3] * qscale);
      lsum += (e0 + e1) + (e2 + e3) + (f0 + f1) + (f2 + f3);
      pt[kh].u[0] = pack_bf16_trunc(e0, e1);
      pt[kh].u[1] = pack_bf16_trunc(e2, e3);
      pt[kh].u[2] = pack_bf16_trunc(f0, f1);
      pt[kh].u[3] = pack_bf16_trunc(f2, f3);
    }
    l_i += lsum;  // cross-lane reduce deferred to epilogue

    // O^T += V^T @ P^T
#pragma unroll
    for (int dt = 0; dt < 4; ++dt)
#pragma unroll
      for (int kh = 0; kh < 2; ++kh) {
        bf16x8 av = *(const bf16x8*)(
            Vs[cur] + (dt * 16 + lo) * 64 + (((kh * 4 + g) ^ lo7) * 8));
        o_acc[dt] = __builtin_amdgcn_mfma_f32_16x16x32_bf16(av, pt[kh].v, o_acc[dt], 0, 0, 0);
      }

    __syncthreads();  // drain prefetch DMAs + release buffer cur
  }

  // epilogue
  l_i += __shfl_xor(l_i, 16);
  l_i += __shfl_xor(l_i, 32);
  const float inv = 1.0f / l_i;
  unsigned short* Es = Ks[0];
#pragma unroll
  for (int dt = 0; dt < 4; ++dt) {
    const int chunk = (dt * 2 + (g >> 1)) ^ lo7;
#pragma unroll
    for (int r = 0; r < 4; ++r)
      Es[(w * 16 + lo) * 64 + chunk * 8 + (g & 1) * 4 + r] =
          f2bf(o_acc[dt][r] * inv);
  }
#pragma unroll
  for (int i = 0; i < 2; ++i) {
    const int row = w * 16 + i * 8 + (lane >> 3);
    bf16x8 val = *(const bf16x8*)(Es + row * 64 + (((lane & 7) ^ (row & 7)) * 8));
    *(bf16x8*)(out + (size_t)(q0 + row) * C_DIM + h * HD + (lane & 7) * 8) = val;
  }
}

// ---------------------------------------------------------------------------
extern "C" void kernel_launch(void* const* d_in, const int* in_sizes, int n_in,
                              void* d_out, int out_size, void* d_ws, size_t ws_size,
                              hipStream_t stream) {
  const float* x      = (const float*)d_in[0];
  const float* w_qkv  = (const float*)d_in[1];
  const float* b_qkv  = (const float*)d_in[2];
  const float* w_proj = (const float*)d_in[3];
  const float* b_proj = (const float*)d_in[4];
  float* out = (float*)d_out;

  unsigned short* xb     = (unsigned short*)d_ws;               // [4096,768]
  unsigned short* wqkvT  = xb + (size_t)T_SEQ * C_DIM;          // [2304,768]
  unsigned short* wprojT = wqkvT + (size_t)C3 * C_DIM;          // [768,768]
  unsigned short* qkv    = wprojT + (size_t)C_DIM * C_DIM;      // [4096,2304]
  unsigned short* vTp    = qkv + (size_t)T_SEQ * C3;            // [768,4096]
  unsigned short* attnb  = vTp + (size_t)C_DIM * T_SEQ;         // [4096,768]

  prep_fused<<<NB_CONV + NB_TQKV + NB_TPROJ, 256, 0, stream>>>(
      x, w_qkv, w_proj, xb, wqkvT, wprojT);

  gemm_qkv<<<dim3(C3 / 128, T_SEQ / 128), 256, 0, stream>>>(
      xb, wqkvT, b_qkv, qkv, vTp, T_SEQ, C3, C_DIM);

  flash_attn_mfma11<<<T_SEQ / 64 * NH, 256, 0, stream>>>(qkv, vTp, attnb);

  gemm_bt_mfma<<<dim3(C_DIM / 128, T_SEQ / 128), 256, 0, stream>>>(
      attnb, wprojT, b_proj, out, T_SEQ, C_DIM, C_DIM);
}

// Round 14
// 186.287 us; speedup vs baseline: 1.1219x; 1.0510x over previous
//
#include <hip/hip_runtime.h>
#include <hip/hip_bf16.h>

// CausalSelfAttention  B=1, T=4096, C=768, H=12, hd=64
// Round 14: revert flash P-packing to R11's per-element f2bf_trunc (the
//   union-based "v_perm" pack was a ~10us codegen regression). Keep BK=64
//   swizzled GEMMs + fused vTp epilogue + monotone-LPT no-max flash.

#define T_SEQ 4096
#define C_DIM 768
#define C3    2304
#define NH    12
#define HD    64

typedef __attribute__((ext_vector_type(8))) short bf16x8;
typedef __attribute__((ext_vector_type(4))) short bf16x4;
typedef __attribute__((ext_vector_type(4))) float f32x4;

__device__ inline unsigned short f2bf(float f) {
  union { float f; unsigned u; } v; v.f = f;
  unsigned r = v.u + 0x7fff + ((v.u >> 16) & 1);  // RTNE
  return (unsigned short)(r >> 16);
}
__device__ inline unsigned short f2bf_trunc(float f) {
  union { float f; unsigned u; } v; v.f = f;
  return (unsigned short)(v.u >> 16);  // truncate: fine for P >= 0
}

__device__ inline void gl2lds16(const void* g, void* l) {
  __builtin_amdgcn_global_load_lds(
      (const __attribute__((address_space(1))) unsigned int*)g,
      (__attribute__((address_space(3))) unsigned int*)l, 16, 0, 0);
}

#if __has_builtin(__builtin_amdgcn_exp2f)
#define EXP2F(x) __builtin_amdgcn_exp2f(x)
#else
#define EXP2F(x) exp2f(x)
#endif

// ---------------------------------------------------------------------------
// fused prep: conv x->bf16 | transpose w_qkv | transpose w_proj
// ---------------------------------------------------------------------------
#define NB_CONV  (T_SEQ * C_DIM / 2048)          // 1536
#define NB_TQKV  ((C3 / 32) * (C_DIM / 32))      // 1728
#define NB_TPROJ ((C_DIM / 32) * (C_DIM / 32))   // 576

__global__ __launch_bounds__(256) void prep_fused(
    const float* __restrict__ x, const float* __restrict__ w_qkv,
    const float* __restrict__ w_proj, unsigned short* __restrict__ xb,
    unsigned short* __restrict__ wqkvT, unsigned short* __restrict__ wprojT) {
  __shared__ float t[32][33];
  const int b = blockIdx.x;
  const int tid = threadIdx.x;

  if (b < NB_CONV) {
    int i = (b * 256 + tid) * 8;
    float4 v0 = *(const float4*)(x + i);
    float4 v1 = *(const float4*)(x + i + 4);
    unsigned short o[8] = {f2bf(v0.x), f2bf(v0.y), f2bf(v0.z), f2bf(v0.w),
                           f2bf(v1.x), f2bf(v1.y), f2bf(v1.z), f2bf(v1.w)};
    *(uint4*)(xb + i) = *(uint4*)o;
    return;
  }
  const float* in;
  unsigned short* outT;
  int R, Cc, bi;
  if (b < NB_CONV + NB_TQKV) {
    in = w_qkv; outT = wqkvT; R = C_DIM; Cc = C3; bi = b - NB_CONV;
  } else {
    in = w_proj; outT = wprojT; R = C_DIM; Cc = C_DIM; bi = b - NB_CONV - NB_TQKV;
  }
  const int tx = tid & 31, ty = tid >> 5;
  const int c0 = (bi % (Cc / 32)) * 32, r0 = (bi / (Cc / 32)) * 32;
#pragma unroll
  for (int i = 0; i < 4; ++i) {
    int r = ty + i * 8;
    t[r][tx] = in[(size_t)(r0 + r) * Cc + c0 + tx];
  }
  __syncthreads();
#pragma unroll
  for (int i = 0; i < 4; ++i) {
    int c = ty + i * 8;
    outT[(size_t)(c0 + c) * R + r0 + tx] = f2bf(t[tx][c]);
  }
}

// ---------------------------------------------------------------------------
// gemm1: qkv = xb @ wqkvT^T + b_qkv; V blocks write k-permuted vTp directly.
// BK=64, XOR-swizzled LDS (chunk c of row r at slot c^(r&7)); 12 k-iters.
// ---------------------------------------------------------------------------
__global__ __launch_bounds__(256) void gemm_qkv(
    const unsigned short* __restrict__ A, const unsigned short* __restrict__ Bt,
    const float* __restrict__ bias, unsigned short* __restrict__ Cq,
    unsigned short* __restrict__ vTp, int M, int N, int K) {
  __shared__ unsigned short As[128 * 64];
  __shared__ unsigned short Bs[128 * 64];
  const int tid = threadIdx.x;
  const int wave = tid >> 6, lane = tid & 63;
  const int lo = lane & 15, g8 = lane >> 4;
  const int lo7 = lo & 7;
  const int wm = wave >> 1, wn = wave & 1;
  const int bm = blockIdx.y * 128, bn = blockIdx.x * 128;
  const int drow8 = lane >> 3;               // 0..7
  const int dslot = (lane & 7) * 8;
  const int dsrc = ((lane & 7) ^ drow8) * 8; // swizzled source chunk

  f32x4 acc[4][4];
#pragma unroll
  for (int mt = 0; mt < 4; ++mt)
#pragma unroll
    for (int nt = 0; nt < 4; ++nt) acc[mt][nt] = (f32x4){0.f, 0.f, 0.f, 0.f};

  const unsigned short* Abase = A + (size_t)bm * K;
  const unsigned short* Bbase = Bt + (size_t)bn * K;

  for (int k0 = 0; k0 < K; k0 += 64) {
    __syncthreads();
#pragma unroll
    for (int p = 0; p < 4; ++p) {
      const int r = p * 32 + wave * 8 + drow8;
      gl2lds16(Abase + (size_t)r * K + k0 + dsrc, As + r * 64 + dslot);
      gl2lds16(Bbase + (size_t)r * K + k0 + dsrc, Bs + r * 64 + dslot);
    }
    __syncthreads();

#pragma unroll
    for (int kk = 0; kk < 2; ++kk) {
      bf16x8 a[4], b[4];
#pragma unroll
      for (int mt = 0; mt < 4; ++mt)
        a[mt] = *(const bf16x8*)(
            As + (wm * 64 + mt * 16 + lo) * 64 + (((kk * 4 + g8) ^ lo7) * 8));
#pragma unroll
      for (int nt = 0; nt < 4; ++nt)
        b[nt] = *(const bf16x8*)(
            Bs + (wn * 64 + nt * 16 + lo) * 64 + (((kk * 4 + g8) ^ lo7) * 8));
#pragma unroll
      for (int mt = 0; mt < 4; ++mt)
#pragma unroll
        for (int nt = 0; nt < 4; ++nt)
          acc[mt][nt] = __builtin_amdgcn_mfma_f32_16x16x32_bf16(a[mt], b[nt], acc[mt][nt], 0, 0, 0);
    }
  }

  if (bn < 2 * C_DIM) {
#pragma unroll
    for (int nt = 0; nt < 4; ++nt) {
      const int n = bn + wn * 64 + nt * 16 + lo;
      const float bv = bias[n];
#pragma unroll
      for (int mt = 0; mt < 4; ++mt)
#pragma unroll
        for (int r = 0; r < 4; ++r) {
          const int m = bm + wm * 64 + mt * 16 + g8 * 4 + r;
          Cq[(size_t)m * C3 + n] = f2bf(acc[mt][nt][r] + bv);
        }
    }
  } else {
#pragma unroll
    for (int nt = 0; nt < 4; ++nt) {
      const int n = bn + wn * 64 + nt * 16 + lo;
      const float bv = bias[n];
      unsigned short* row = vTp + (size_t)(n - 2 * C_DIM) * T_SEQ;
#pragma unroll
      for (int mt = 0; mt < 4; ++mt) {
        const int mbase = (bm + wm * 64 + mt * 16 + g8 * 4) & ~31;
        bf16x4 o4;
#pragma unroll
        for (int r = 0; r < 4; ++r) o4[r] = (short)f2bf(acc[mt][nt][r] + bv);
        *(bf16x4*)(row + mbase + 8 * g8 + 4 * (mt & 1)) = o4;
      }
    }
  }
}

// ---------------------------------------------------------------------------
// gemm2: bf16 MFMA GEMM, B^T input, fp32 out. BK=64 swizzled (as gemm1).
// ---------------------------------------------------------------------------
__global__ __launch_bounds__(256) void gemm_bt_mfma(
    const unsigned short* __restrict__ A, const unsigned short* __restrict__ Bt,
    const float* __restrict__ bias, float* __restrict__ C,
    int M, int N, int K) {
  __shared__ unsigned short As[128 * 64];
  __shared__ unsigned short Bs[128 * 64];
  const int tid = threadIdx.x;
  const int wave = tid >> 6, lane = tid & 63;
  const int lo = lane & 15, g8 = lane >> 4;
  const int lo7 = lo & 7;
  const int wm = wave >> 1, wn = wave & 1;
  const int bm = blockIdx.y * 128, bn = blockIdx.x * 128;
  const int drow8 = lane >> 3;
  const int dslot = (lane & 7) * 8;
  const int dsrc = ((lane & 7) ^ drow8) * 8;

  f32x4 acc[4][4];
#pragma unroll
  for (int mt = 0; mt < 4; ++mt)
#pragma unroll
    for (int nt = 0; nt < 4; ++nt) acc[mt][nt] = (f32x4){0.f, 0.f, 0.f, 0.f};

  const unsigned short* Abase = A + (size_t)bm * K;
  const unsigned short* Bbase = Bt + (size_t)bn * K;

  for (int k0 = 0; k0 < K; k0 += 64) {
    __syncthreads();
#pragma unroll
    for (int p = 0; p < 4; ++p) {
      const int r = p * 32 + wave * 8 + drow8;
      gl2lds16(Abase + (size_t)r * K + k0 + dsrc, As + r * 64 + dslot);
      gl2lds16(Bbase + (size_t)r * K + k0 + dsrc, Bs + r * 64 + dslot);
    }
    __syncthreads();

#pragma unroll
    for (int kk = 0; kk < 2; ++kk) {
      bf16x8 a[4], b[4];
#pragma unroll
      for (int mt = 0; mt < 4; ++mt)
        a[mt] = *(const bf16x8*)(
            As + (wm * 64 + mt * 16 + lo) * 64 + (((kk * 4 + g8) ^ lo7) * 8));
#pragma unroll
      for (int nt = 0; nt < 4; ++nt)
        b[nt] = *(const bf16x8*)(
            Bs + (wn * 64 + nt * 16 + lo) * 64 + (((kk * 4 + g8) ^ lo7) * 8));
#pragma unroll
      for (int mt = 0; mt < 4; ++mt)
#pragma unroll
        for (int nt = 0; nt < 4; ++nt)
          acc[mt][nt] = __builtin_amdgcn_mfma_f32_16x16x32_bf16(a[mt], b[nt], acc[mt][nt], 0, 0, 0);
    }
  }

#pragma unroll
  for (int nt = 0; nt < 4; ++nt) {
    const int n = bn + wn * 64 + nt * 16 + lo;
    const float bv = bias[n];
#pragma unroll
    for (int mt = 0; mt < 4; ++mt)
#pragma unroll
      for (int r = 0; r < 4; ++r) {
        const int m = bm + wm * 64 + mt * 16 + g8 * 4 + r;
        C[(size_t)m * N + n] = acc[mt][nt][r] + bv;
      }
  }
}

// ---------------------------------------------------------------------------
// flash v12 = R11's v9 exactly: monotone LPT (stream-aligned), no-max
// softmax with per-element f2bf_trunc pack, reg-resident P, swizzled K/V
// double-buffer, lds-DMA staging, LDS-bounce epilogue.
// ---------------------------------------------------------------------------
__global__ __launch_bounds__(256) void flash_attn_mfma12(
    const unsigned short* __restrict__ qkv,   // [T][2304] bf16 (Q,K valid)
    const unsigned short* __restrict__ vTp,   // [768][T] bf16, k-permuted
    unsigned short* __restrict__ out) {       // [T][768] bf16
  __shared__ unsigned short Ks[2][64 * 64];
  __shared__ unsigned short Vs[2][64 * 64];

  const int qt = 63 - blockIdx.x / NH;  // monotone LPT (stream-aligned)
  const int h = blockIdx.x % NH;
  const int q0 = qt * 64;
  const int tid = threadIdx.x;
  const int w = tid >> 6;
  const int lane = tid & 63;
  const int lo = lane & 15;
  const int g = lane >> 4;
  const int lo7 = lo & 7;
  const float qscale = 0.125f * 1.44269504f;  // 1/sqrt(64) * log2(e)

  const unsigned short* Kg = qkv + C_DIM + h * HD;           // row stride C3
  const unsigned short* Vg = vTp + (size_t)(h * HD) * T_SEQ; // row stride T_SEQ

  const int drow = tid >> 3;                    // 0..31
  const int dslot = (tid & 7) * 8;
  const int dsrc = ((tid & 7) ^ (drow & 7)) * 8;

  // Q B-frags direct from global (one-time)
  bf16x8 qb[2];
#pragma unroll
  for (int dh = 0; dh < 2; ++dh)
    qb[dh] = *(const bf16x8*)(
        qkv + (size_t)(q0 + w * 16 + lo) * C3 + h * HD + dh * 32 + g * 8);

  // prologue: DMA tile 0
#pragma unroll
  for (int p = 0; p < 2; ++p) {
    const int r = p * 32 + drow;
    gl2lds16(Kg + (size_t)r * C3 + dsrc, Ks[0] + r * 64 + dslot);
    gl2lds16(Vg + (size_t)r * T_SEQ + dsrc, Vs[0] + r * 64 + dslot);
  }
  __syncthreads();

  float l_i = 0.f;
  f32x4 o_acc[4];
#pragma unroll
  for (int dt = 0; dt < 4; ++dt) o_acc[dt] = (f32x4){0.f, 0.f, 0.f, 0.f};

  for (int t = 0; t <= qt; ++t) {
    const int cur = t & 1;
    if (t < qt) {
      const int k0n = (t + 1) * 64;
#pragma unroll
      for (int p = 0; p < 2; ++p) {
        const int r = p * 32 + drow;
        gl2lds16(Kg + (size_t)(k0n + r) * C3 + dsrc, Ks[cur ^ 1] + r * 64 + dslot);
        gl2lds16(Vg + (size_t)r * T_SEQ + k0n + dsrc, Vs[cur ^ 1] + r * 64 + dslot);
      }
    }

    // St = K @ Q^T
    f32x4 st[4];
#pragma unroll
    for (int mt = 0; mt < 4; ++mt) st[mt] = (f32x4){0.f, 0.f, 0.f, 0.f};
#pragma unroll
    for (int mt = 0; mt < 4; ++mt)
#pragma unroll
      for (int dh = 0; dh < 2; ++dh) {
        bf16x8 a = *(const bf16x8*)(
            Ks[cur] + (mt * 16 + lo) * 64 + (((dh * 4 + g) ^ lo7) * 8));
        st[mt] = __builtin_amdgcn_mfma_f32_16x16x32_bf16(a, qb[dh], st[mt], 0, 0, 0);
      }

    // causal mask (last tile only) -> exact zeros after exp2
    if (t == qt) {
      const int qloc = w * 16 + lo;
#pragma unroll
      for (int mt = 0; mt < 4; ++mt)
#pragma unroll
        for (int r = 0; r < 4; ++r)
          if (mt * 16 + g * 4 + r > qloc) st[mt][r] = -1e30f;
    }

    // no-max softmax: e = exp2(s * qscale)  (R11 codegen — per-element pack)
    float lsum = 0.f;
    bf16x8 pt[2];
#pragma unroll
    for (int kh = 0; kh < 2; ++kh) {
#pragma unroll
      for (int j = 0; j < 4; ++j) {
        float e0 = EXP2F(st[kh * 2][j] * qscale);
        float e1 = EXP2F(st[kh * 2 + 1][j] * qscale);
        lsum += e0 + e1;
        pt[kh][j] = (short)f2bf_trunc(e0);
        pt[kh][4 + j] = (short)f2bf_trunc(e1);
      }
    }
    l_i += lsum;  // cross-lane reduce deferred to epilogue

    // O^T += V^T @ P^T
#pragma unroll
    for (int dt = 0; dt < 4; ++dt)
#pragma unroll
      for (int kh = 0; kh < 2; ++kh) {
        bf16x8 av = *(const bf16x8*)(
            Vs[cur] + (dt * 16 + lo) * 64 + (((kh * 4 + g) ^ lo7) * 8));
        o_acc[dt] = __builtin_amdgcn_mfma_f32_16x16x32_bf16(av, pt[kh], o_acc[dt], 0, 0, 0);
      }

    __syncthreads();  // drain prefetch DMAs + release buffer cur
  }

  // epilogue
  l_i += __shfl_xor(l_i, 16);
  l_i += __shfl_xor(l_i, 32);
  const float inv = 1.0f / l_i;
  unsigned short* Es = Ks[0];
#pragma unroll
  for (int dt = 0; dt < 4; ++dt) {
    const int chunk = (dt * 2 + (g >> 1)) ^ lo7;
#pragma unroll
    for (int r = 0; r < 4; ++r)
      Es[(w * 16 + lo) * 64 + chunk * 8 + (g & 1) * 4 + r] =
          f2bf(o_acc[dt][r] * inv);
  }
#pragma unroll
  for (int i = 0; i < 2; ++i) {
    const int row = w * 16 + i * 8 + (lane >> 3);
    bf16x8 val = *(const bf16x8*)(Es + row * 64 + (((lane & 7) ^ (row & 7)) * 8));
    *(bf16x8*)(out + (size_t)(q0 + row) * C_DIM + h * HD + (lane & 7) * 8) = val;
  }
}

// ---------------------------------------------------------------------------
extern "C" void kernel_launch(void* const* d_in, const int* in_sizes, int n_in,
                              void* d_out, int out_size, void* d_ws, size_t ws_size,
                              hipStream_t stream) {
  const float* x      = (const float*)d_in[0];
  const float* w_qkv  = (const float*)d_in[1];
  const float* b_qkv  = (const float*)d_in[2];
  const float* w_proj = (const float*)d_in[3];
  const float* b_proj = (const float*)d_in[4];
  float* out = (float*)d_out;

  unsigned short* xb     = (unsigned short*)d_ws;               // [4096,768]
  unsigned short* wqkvT  = xb + (size_t)T_SEQ * C_DIM;          // [2304,768]
  unsigned short* wprojT = wqkvT + (size_t)C3 * C_DIM;          // [768,768]
  unsigned short* qkv    = wprojT + (size_t)C_DIM * C_DIM;      // [4096,2304]
  unsigned short* vTp    = qkv + (size_t)T_SEQ * C3;            // [768,4096]
  unsigned short* attnb  = vTp + (size_t)C_DIM * T_SEQ;         // [4096,768]

  prep_fused<<<NB_CONV + NB_TQKV + NB_TPROJ, 256, 0, stream>>>(
      x, w_qkv, w_proj, xb, wqkvT, wprojT);

  gemm_qkv<<<dim3(C3 / 128, T_SEQ / 128), 256, 0, stream>>>(
      xb, wqkvT, b_qkv, qkv, vTp, T_SEQ, C3, C_DIM);

  flash_attn_mfma12<<<T_SEQ / 64 * NH, 256, 0, stream>>>(qkv, vTp, attnb);

  gemm_bt_mfma<<<dim3(C_DIM / 128, T_SEQ / 128), 256, 0, stream>>>(
      attnb, wprojT, b_proj, out, T_SEQ, C_DIM, C_DIM);
}